// Round 10
// baseline (17.129 us; speedup 1.0000x reference)
//
#include <hip/hip_runtime.h>
#include <hip/hip_bf16.h>

#define TD 512
#define SD 128
#define NT 8
#define BATCH 16384
#define BR 32              // rows per block

typedef float f32x4 __attribute__((ext_vector_type(4)));
typedef short s16x8 __attribute__((ext_vector_type(8)));
typedef unsigned short u16;
typedef unsigned long long u64;

__device__ __forceinline__ u16 f2bf(float f) {
    return __builtin_bit_cast(u16, __float2bfloat16(f));   // RNE
}
__device__ __forceinline__ u64 pack4bf(f32x4 v) {
    u16 a[4];
    #pragma unroll
    for (int j = 0; j < 4; ++j) a[j] = f2bf(v[j]);
    return __builtin_bit_cast(u64, *(ushort4*)a);
}

// Single kernel. Grid 512 x 256 thr (4 waves). Block = 32 rows x 128 N x 512 K.
// LDS: A rows bf16 swizzled (32 KB) + W-frag ping-pong 2 x 16 KB (K-chunk 64)
// = 64 KB -> 2 blocks/CU: block-level overlap of gather latency, barrier
// drains, and hit-count tail. 8 chunks, 1 barrier each.
__global__ __launch_bounds__(256, 2) void fused_kernel(
    const float* __restrict__ emb,            // [500000][512]
    const float* __restrict__ clogits,        // [500000][8]
    const float* __restrict__ W,              // [512][128]
    const int* __restrict__ slot,             // [16384]
    const int* __restrict__ hit,              // [16384] int32 bool
    float* __restrict__ feats_out,            // [16384][128]
    float* __restrict__ logits_out)           // [16384][8]
{
    __shared__ __align__(16) char Al[BR * TD * 2];    // 32 KiB
    __shared__ __align__(16) char Wf[2][16384];       // 32 KiB

    const int tid  = threadIdx.x;
    const int w    = tid >> 6;
    const int lane = tid & 63;
    const int m0b  = blockIdx.x * BR;

    // ---- gather: wave w owns rows w*8..w*8+7, 1 KB contiguous per instr ----
    f32x4 rg[8][2];
    #pragma unroll
    for (int r = 0; r < 8; ++r) {
        const int grow = m0b + w * 8 + r;
        if (hit[grow]) {                       // wave-uniform branch
            const float* rp = emb + (long)slot[grow] * TD + lane * 4;
            rg[r][0] = *(const f32x4*)rp;
            rg[r][1] = *(const f32x4*)(rp + 256);
        } else {
            rg[r][0] = (f32x4){0.f, 0.f, 0.f, 0.f};
            rg[r][1] = (f32x4){0.f, 0.f, 0.f, 0.f};
        }
    }

    // ---- logits: 32 rows x 8 = 256, one per thread ----
    const int lrow = m0b + (tid >> 3);
    const int lj   = tid & 7;
    float lv = 0.f;
    if (hit[lrow]) lv = clogits[(long)slot[lrow] * NT + lj];

    // W chunk c (K 64): unit s = tid + 256*i (i<4); lane_u=s&63, ksu=(s>>6)&1,
    // cg=s>>7. value j: W[c*64 + ksu*32 + (lane_u>>4)*8 + j][cg*16+(lane_u&15)]
    // Wf unit addr = ((cg*2 + ksu)*64 + lane_u)*16.
#define STAGE_LOAD(c, WS)                                                     \
    {                                                                         \
        _Pragma("unroll")                                                     \
        for (int i = 0; i < 4; ++i) {                                         \
            const int s = tid + 256 * i;                                      \
            const int lu = s & 63;                                            \
            const int kbase = (c) * 64 + ((s >> 6) & 1) * 32 +                \
                              ((lu >> 4)) * 8;                                \
            const int n = (s >> 7) * 16 + (lu & 15);                          \
            _Pragma("unroll")                                                 \
            for (int j = 0; j < 8; ++j)                                       \
                WS[i * 8 + j] = W[(kbase + j) * SD + n];                      \
        }                                                                     \
    }

#define STAGE_WRITE(buf, WS)                                                  \
    {                                                                         \
        _Pragma("unroll")                                                     \
        for (int i = 0; i < 4; ++i) {                                         \
            const int s = tid + 256 * i;                                      \
            const int lu = s & 63;                                            \
            const int u = (((s >> 7) * 2 + ((s >> 6) & 1)) * 64 + lu);        \
            u16 v[8];                                                         \
            _Pragma("unroll")                                                 \
            for (int j = 0; j < 8; ++j) v[j] = f2bf(WS[i * 8 + j]);           \
            *(s16x8*)(Wf[buf] + u * 16) = *(const s16x8*)v;                   \
        }                                                                     \
    }

    float wsA[32], wsB[32];
    STAGE_LOAD(0, wsA);

    // ---- A -> LDS (bf16, XOR-swizzled rows) ----
    #pragma unroll
    for (int r = 0; r < 8; ++r) {
        const int rowL = w * 8 + r;
        const int swz = (rowL & 7) << 4;
        const int b0 = (rowL << 10) | (lane << 3);
        *(u64*)(Al + (b0 ^ swz))         = pack4bf(rg[r][0]);
        *(u64*)(Al + ((b0 + 512) ^ swz)) = pack4bf(rg[r][1]);
    }
    logits_out[(long)lrow * NT + lj] = lv;

    STAGE_WRITE(0, wsA);
    STAGE_LOAD(1, wsB);

    // ---- compute identity: wave -> row-group g (16 rows), N-half h ----
    const int g = w >> 1;
    const int h = w & 1;
    const int lr16 = lane & 15;
    const int kb   = lane >> 4;
    const int rowL = g * 16 + lr16;
    const int aswz = (rowL & 7) << 4;

    f32x4 acc[4];
    #pragma unroll
    for (int t = 0; t < 4; ++t) acc[t] = (f32x4){0.f, 0.f, 0.f, 0.f};

#define COMPUTE(c, buf)                                                       \
    {                                                                         \
        _Pragma("unroll")                                                     \
        for (int s4 = 0; s4 < 2; ++s4) {                                      \
            const int abyte = ((rowL << 10) |                                 \
                               ((c) * 128 + s4 * 64 + kb * 16)) ^ aswz;       \
            const s16x8 a = *(const s16x8*)(Al + abyte);                      \
            _Pragma("unroll")                                                 \
            for (int t = 0; t < 4; ++t) {                                     \
                const s16x8 b = *(const s16x8*)(Wf[buf] +                     \
                    ((((h * 4 + t) * 2 + s4) * 64 + lane) * 16));             \
                acc[t] = __builtin_amdgcn_mfma_f32_16x16x32_bf16(             \
                             a, b, acc[t], 0, 0, 0);                          \
            }                                                                 \
        }                                                                     \
    }

    __syncthreads();                    // A + W0 ready
    #pragma unroll
    for (int c = 0; c < 8; ++c) {
        if (c & 1) COMPUTE(c, 1) else COMPUTE(c, 0);
        if (c < 7) {
            // chunk c+1 regs: set (c+1)&1 (wsB for even c); load c+2 into c&1
            if (c & 1) { STAGE_WRITE((c + 1) & 1, wsA); }
            else       { STAGE_WRITE((c + 1) & 1, wsB); }
            if (c < 6) {
                if (c & 1) { STAGE_LOAD(c + 2, wsB); }
                else       { STAGE_LOAD(c + 2, wsA); }
            }
            __syncthreads();
        }
    }

#undef STAGE_LOAD
#undef STAGE_WRITE
#undef COMPUTE

    // ---- feats store: D row = kb*4+i, col = (h*4+t)*16 + lr16 ----
    #pragma unroll
    for (int t = 0; t < 4; ++t)
        #pragma unroll
        for (int i = 0; i < 4; ++i)
            feats_out[(long)(m0b + g * 16 + kb * 4 + i) * SD +
                      (h * 4 + t) * 16 + lr16] = acc[t][i];
}

extern "C" void kernel_launch(void* const* d_in, const int* in_sizes, int n_in,
                              void* d_out, int out_size, void* d_ws, size_t ws_size,
                              hipStream_t stream) {
    const float* cache_emb    = (const float*)d_in[0];
    const float* cache_logits = (const float*)d_in[1];
    const float* W            = (const float*)d_in[2];
    const int*   slot_idx     = (const int*)d_in[3];
    const int*   hitm         = (const int*)d_in[4];

    float* feats_out  = (float*)d_out;                       // 16384*128
    float* logits_out = (float*)d_out + (long)BATCH * SD;    // 16384*8

    fused_kernel<<<BATCH / BR, 256, 0, stream>>>(cache_emb, cache_logits, W,
                                                 slot_idx, hitm,
                                                 feats_out, logits_out);
}

// Round 11
// 15.041 us; speedup vs baseline: 1.1389x; 1.1389x over previous
//
#include <hip/hip_runtime.h>
#include <hip/hip_bf16.h>

#define TD 512
#define SD 128
#define NT 8
#define BATCH 16384
#define BR 64              // rows per block

typedef float f32x4 __attribute__((ext_vector_type(4)));
typedef short s16x8 __attribute__((ext_vector_type(8)));
typedef unsigned short u16;
typedef unsigned long long u64;

__device__ __forceinline__ u16 f2bf(float f) {
    return __builtin_bit_cast(u16, __float2bfloat16(f));   // RNE
}
__device__ __forceinline__ u64 pack4bf(f32x4 v) {
    u16 a[4];
    #pragma unroll
    for (int j = 0; j < 4; ++j) a[j] = f2bf(v[j]);
    return __builtin_bit_cast(u64, *(ushort4*)a);
}

// Single kernel. Grid 256 x 512 thr (8 waves). Block = 64 rows x 128 N x 512 K.
// LDS: A rows bf16 swizzled (64 KB) + W-fragment ping-pong buffers (2 x 32 KB).
// W staged per 128-K chunk: scalar f32 loads (L2-hot) -> pack -> conflict-free
// ds_write_b128 in MFMA-B lane order. Gather: wave-cooperative, 1 KB/instr,
// wave-uniform skip of miss rows. 4 barriers total.
__global__ __launch_bounds__(512, 2) void fused_kernel(
    const float* __restrict__ emb,            // [500000][512]
    const float* __restrict__ clogits,        // [500000][8]
    const float* __restrict__ W,              // [512][128]
    const int* __restrict__ slot,             // [16384]
    const int* __restrict__ hit,              // [16384] int32 bool
    float* __restrict__ feats_out,            // [16384][128]
    float* __restrict__ logits_out)           // [16384][8]
{
    __shared__ __align__(16) char Al[BR * TD * 2];    // 64 KiB
    __shared__ __align__(16) char Wf[2][32768];       // 64 KiB

    const int tid  = threadIdx.x;
    const int w    = tid >> 6;
    const int lane = tid & 63;
    const int m0b  = blockIdx.x * BR;

    // ---- gather: wave w owns rows w*8..w*8+7, 1 KB contiguous per instr ----
    f32x4 rg[8][2];
    #pragma unroll
    for (int r = 0; r < 8; ++r) {
        const int grow = m0b + w * 8 + r;
        if (hit[grow]) {                       // wave-uniform branch
            const float* rp = emb + (long)slot[grow] * TD + lane * 4;
            rg[r][0] = *(const f32x4*)rp;
            rg[r][1] = *(const f32x4*)(rp + 256);
        } else {
            rg[r][0] = (f32x4){0.f, 0.f, 0.f, 0.f};
            rg[r][1] = (f32x4){0.f, 0.f, 0.f, 0.f};
        }
    }

    // ---- W chunk c slot map: s = tid + 512*i -> lane=s&63, ks=(s>>6)&3,
    //      cg=(s>>8)&7; value j: W[c*128 + ks*32 + ((s>>4)&3)*8 + j][cg*16+(s&15)]
#define STAGE_LOAD(c, WS)                                                     \
    {                                                                         \
        _Pragma("unroll")                                                     \
        for (int i = 0; i < 4; ++i) {                                         \
            const int s = tid + 512 * i;                                      \
            const int kbase = (c) * 128 + ((s >> 6) & 3) * 32 +               \
                              ((s >> 4) & 3) * 8;                             \
            const int n = ((s >> 8) & 7) * 16 + (s & 15);                     \
            _Pragma("unroll")                                                 \
            for (int j = 0; j < 8; ++j)                                       \
                WS[i * 8 + j] = W[(kbase + j) * SD + n];                      \
        }                                                                     \
    }

#define STAGE_WRITE(buf, WS)                                                  \
    {                                                                         \
        _Pragma("unroll")                                                     \
        for (int i = 0; i < 4; ++i) {                                         \
            u16 v[8];                                                         \
            _Pragma("unroll")                                                 \
            for (int j = 0; j < 8; ++j) v[j] = f2bf(WS[i * 8 + j]);           \
            *(s16x8*)(Wf[buf] + (tid + 512 * i) * 16) = *(const s16x8*)v;     \
        }                                                                     \
    }

    // ---- logits (issued alongside; 1 per thread) ----
    const int lrow = m0b + (tid >> 3);
    const int lj   = tid & 7;
    float lv = 0.f;
    if (hit[lrow]) lv = clogits[(long)slot[lrow] * NT + lj];

    float wsA[32], wsB[32];
    STAGE_LOAD(0, wsA);

    // ---- A -> LDS (bf16, XOR-swizzled rows) ----
    #pragma unroll
    for (int r = 0; r < 8; ++r) {
        const int rowL = w * 8 + r;
        const int swz = (rowL & 7) << 4;
        const int b0 = (rowL << 10) | (lane << 3);
        *(u64*)(Al + (b0 ^ swz))         = pack4bf(rg[r][0]);
        *(u64*)(Al + ((b0 + 512) ^ swz)) = pack4bf(rg[r][1]);
    }
    logits_out[(long)lrow * NT + lj] = lv;

    STAGE_WRITE(0, wsA);
    STAGE_LOAD(1, wsB);

    // ---- compute identity: wave -> row-group g, N-half h ----
    const int g = w >> 1;
    const int h = w & 1;
    const int lr16 = lane & 15;
    const int kb   = lane >> 4;
    const int rowL = g * 16 + lr16;
    const int aswz = (rowL & 7) << 4;

    f32x4 acc[4];
    #pragma unroll
    for (int t = 0; t < 4; ++t) acc[t] = (f32x4){0.f, 0.f, 0.f, 0.f};

#define COMPUTE(c, buf)                                                       \
    {                                                                         \
        _Pragma("unroll")                                                     \
        for (int s4 = 0; s4 < 4; ++s4) {                                      \
            const int abyte = ((rowL << 10) |                                 \
                               ((c) * 256 + s4 * 64 + kb * 16)) ^ aswz;       \
            const s16x8 a = *(const s16x8*)(Al + abyte);                      \
            _Pragma("unroll")                                                 \
            for (int t = 0; t < 4; ++t) {                                     \
                const s16x8 b = *(const s16x8*)(Wf[buf] +                     \
                    (((h * 4 + t) * 4 + s4) * 64 + lane) * 16);               \
                acc[t] = __builtin_amdgcn_mfma_f32_16x16x32_bf16(             \
                             a, b, acc[t], 0, 0, 0);                          \
            }                                                                 \
        }                                                                     \
    }

    __syncthreads();            // bar1: A + frag c0 ready
    COMPUTE(0, 0);
    STAGE_WRITE(1, wsB);
    STAGE_LOAD(2, wsA);
    __syncthreads();            // bar2: frag c1 ready; c0 reads done
    COMPUTE(1, 1);
    STAGE_WRITE(0, wsA);        // c2 -> bufA (last read ended at bar2)
    STAGE_LOAD(3, wsB);
    __syncthreads();            // bar3: frag c2 ready; c1 reads done
    COMPUTE(2, 0);
    STAGE_WRITE(1, wsB);        // c3 -> bufB (last read ended at bar3)
    __syncthreads();            // bar4: frag c3 ready
    COMPUTE(3, 1);

#undef STAGE_LOAD
#undef STAGE_WRITE
#undef COMPUTE

    // ---- feats store: D row = kb*4+i, col = (h*4+t)*16 + lr16 ----
    #pragma unroll
    for (int t = 0; t < 4; ++t)
        #pragma unroll
        for (int i = 0; i < 4; ++i)
            feats_out[(long)(m0b + g * 16 + kb * 4 + i) * SD +
                      (h * 4 + t) * 16 + lr16] = acc[t][i];
}

extern "C" void kernel_launch(void* const* d_in, const int* in_sizes, int n_in,
                              void* d_out, int out_size, void* d_ws, size_t ws_size,
                              hipStream_t stream) {
    const float* cache_emb    = (const float*)d_in[0];
    const float* cache_logits = (const float*)d_in[1];
    const float* W            = (const float*)d_in[2];
    const int*   slot_idx     = (const int*)d_in[3];
    const int*   hitm         = (const int*)d_in[4];

    float* feats_out  = (float*)d_out;                       // 16384*128
    float* logits_out = (float*)d_out + (long)BATCH * SD;    // 16384*8

    fused_kernel<<<BATCH / BR, 512, 0, stream>>>(cache_emb, cache_logits, W,
                                                 slot_idx, hitm,
                                                 feats_out, logits_out);
}